// Round 3
// baseline (149.673 us; speedup 1.0000x reference)
//
#include <hip/hip_runtime.h>

#define NSYS 64
#define NAT  1000
#define NTOT (NSYS * NAT)          // 64000
#define NPAD (NTOT + 256)          // SoA arrays padded for float4 over-read
#define MP   2200000               // MAX_PAIRS
#define CUT2 25.0f                 // cutoff^2
#define PADV 64000.0f              // padding_value = n
#define SCAN_BLOCKS 250            // 250 * 256 == 64000 exactly

// Identical distance expression in count & write passes (must match bit-exactly
// so row offsets stay consistent).
__device__ __forceinline__ float dist2f(float xi, float yi, float zi,
                                        float xj, float yj, float zj) {
    float dx = xi - xj, dy = yi - yj, dz = zi - zj;
    return fmaf(dz, dz, fmaf(dy, dy, dx * dx));
}

// AoS (64000,3) -> SoA xs/ys/zs; zero the 256-element tail slack.
__global__ void k_transpose(const float* __restrict__ c,
                            float* __restrict__ xs, float* __restrict__ ys,
                            float* __restrict__ zs) {
    int a = blockIdx.x * blockDim.x + threadIdx.x;
    if (a < NTOT) {
        xs[a] = c[3 * a + 0];
        ys[a] = c[3 * a + 1];
        zs[a] = c[3 * a + 2];
    } else if (a < NPAD) {
        xs[a] = 1.0e30f; ys[a] = 1.0e30f; zs[a] = 1.0e30f;
    }
}

// One wave per row (s,i): count kept pairs j in (i, NAT).
// Vectorized: each lane evaluates 4 consecutive j via float4 SoA loads.
__global__ void k_count(const float* __restrict__ xs, const float* __restrict__ ys,
                        const float* __restrict__ zs, int* __restrict__ counts) {
    int gt   = blockIdx.x * blockDim.x + threadIdx.x;
    int row  = gt >> 6;
    int lane = threadIdx.x & 63;
    if (row >= NTOT) return;
    int i       = row % NAT;
    int rowbase = row - i;                       // s*NAT
    float xi = xs[row], yi = ys[row], zi = zs[row];
    int cnt = 0;
    int j1 = i + 1;
    int jA = (j1 + 3) & ~3;                      // align start to 4
    if (jA > NAT) jA = NAT;
    {   // scalar prologue: j in [j1, jA)
        int j = j1 + lane;
        if (j < jA) {
            int b = rowbase + j;
            float d2 = dist2f(xi, yi, zi, xs[b], ys[b], zs[b]);
            cnt += (d2 < CUT2) ? 1 : 0;
        }
    }
    for (int j0 = jA; j0 < NAT; j0 += 256) {     // 256 candidates per chunk
        int jb = j0 + 4 * lane;
        int b  = rowbase + jb;
        float4 vx = *(const float4*)(xs + b);
        float4 vy = *(const float4*)(ys + b);
        float4 vz = *(const float4*)(zs + b);
        float d0 = dist2f(xi, yi, zi, vx.x, vy.x, vz.x);
        float d1 = dist2f(xi, yi, zi, vx.y, vy.y, vz.y);
        float d2 = dist2f(xi, yi, zi, vx.z, vy.z, vz.z);
        float d3 = dist2f(xi, yi, zi, vx.w, vy.w, vz.w);
        cnt += (jb + 0 < NAT && d0 < CUT2) ? 1 : 0;
        cnt += (jb + 1 < NAT && d1 < CUT2) ? 1 : 0;
        cnt += (jb + 2 < NAT && d2 < CUT2) ? 1 : 0;
        cnt += (jb + 3 < NAT && d3 < CUT2) ? 1 : 0;
    }
    for (int off = 32; off > 0; off >>= 1) cnt += __shfl_xor(cnt, off, 64);
    if (lane == 0) counts[row] = cnt;
}

// Level-1 scan: 250 blocks x 256 rows. In-place block-exclusive values,
// plus one block sum per block.
__global__ void k_scan_a(int* __restrict__ counts, int* __restrict__ bsum) {
    __shared__ int tmp[256];
    int t = threadIdx.x;
    int g = blockIdx.x * 256 + t;
    int v = counts[g];
    tmp[t] = v;
    __syncthreads();
    for (int off = 1; off < 256; off <<= 1) {
        int u = (t >= off) ? tmp[t - off] : 0;
        __syncthreads();
        tmp[t] += u;
        __syncthreads();
    }
    counts[g] = tmp[t] - v;
    if (t == 255) bsum[blockIdx.x] = tmp[255];
}

// Level-2 scan: one block scans the 250 block sums, writes grand total.
__global__ void k_scan_b(int* __restrict__ bsum, int* __restrict__ total) {
    __shared__ int tmp[256];
    int t = threadIdx.x;
    int v = (t < SCAN_BLOCKS) ? bsum[t] : 0;
    tmp[t] = v;
    __syncthreads();
    for (int off = 1; off < 256; off <<= 1) {
        int u = (t >= off) ? tmp[t - off] : 0;
        __syncthreads();
        tmp[t] += u;
        __syncthreads();
    }
    if (t < SCAN_BLOCKS) bsum[t] = tmp[t] - v;
    if (t == 255) *total = tmp[255];
}

__device__ __forceinline__ void write6(float* __restrict__ out, int pos,
                                       float fs, float fd, float d2) {
    if (pos < MP) {
        out[pos]          = fs;
        out[MP + pos]     = fd;
        out[2 * MP + pos] = fd;
        out[3 * MP + pos] = fs;
        out[4 * MP + pos] = d2;
        out[5 * MP + pos] = d2;
    }
}

// One wave per row: recompute keep mask (vectorized 4/lane), write pairs at
// offset + exact (s,i,j)-ordered rank via 4 ballots per 256-candidate chunk.
// Out layout (floats): [0,MP) src | [MP,2MP) dst | [2MP,3MP) dst | [3MP,4MP) src
//                      | [4MP,5MP) d12 | [5MP,6MP) d12 | [6MP] npairs
__global__ void k_write(const float* __restrict__ xs, const float* __restrict__ ys,
                        const float* __restrict__ zs, const int* __restrict__ offsets,
                        const int* __restrict__ bsum, float* __restrict__ out) {
    int gt   = blockIdx.x * blockDim.x + threadIdx.x;
    int row  = gt >> 6;
    int lane = threadIdx.x & 63;
    if (row >= NTOT) return;
    int i       = row % NAT;
    int rowbase = row - i;
    float xi = xs[row], yi = ys[row], zi = zs[row];
    float fs = (float)row;
    int running = offsets[row] + bsum[row >> 8]; // global exclusive prefix
    unsigned long long lt = (1ull << lane) - 1ull;
    int j1 = i + 1;
    int jA = (j1 + 3) & ~3;
    if (jA > NAT) jA = NAT;
    {   // scalar prologue: j in [j1, jA)
        int j = j1 + lane;
        bool keep = false;
        float d2  = 0.0f;
        int   b   = rowbase + j;
        if (j < jA) {
            d2   = dist2f(xi, yi, zi, xs[b], ys[b], zs[b]);
            keep = (d2 < CUT2);
        }
        unsigned long long m = __ballot(keep);
        if (keep) write6(out, running + (int)__popcll(m & lt), fs, (float)b, d2);
        running += (int)__popcll(m);
    }
    for (int j0 = jA; j0 < NAT; j0 += 256) {
        int jb = j0 + 4 * lane;
        int b  = rowbase + jb;
        float4 vx = *(const float4*)(xs + b);
        float4 vy = *(const float4*)(ys + b);
        float4 vz = *(const float4*)(zs + b);
        float e0 = dist2f(xi, yi, zi, vx.x, vy.x, vz.x);
        float e1 = dist2f(xi, yi, zi, vx.y, vy.y, vz.y);
        float e2 = dist2f(xi, yi, zi, vx.z, vy.z, vz.z);
        float e3 = dist2f(xi, yi, zi, vx.w, vy.w, vz.w);
        bool k0 = (jb + 0 < NAT) && (e0 < CUT2);
        bool k1 = (jb + 1 < NAT) && (e1 < CUT2);
        bool k2 = (jb + 2 < NAT) && (e2 < CUT2);
        bool k3 = (jb + 3 < NAT) && (e3 < CUT2);
        unsigned long long m0 = __ballot(k0);
        unsigned long long m1 = __ballot(k1);
        unsigned long long m2 = __ballot(k2);
        unsigned long long m3 = __ballot(k3);
        if (m0 | m1 | m2 | m3) {
            int base = running + (int)__popcll(m0 & lt) + (int)__popcll(m1 & lt)
                               + (int)__popcll(m2 & lt) + (int)__popcll(m3 & lt);
            int w = 0;
            if (k0) { write6(out, base + w, fs, (float)(b + 0), e0); w++; }
            if (k1) { write6(out, base + w, fs, (float)(b + 1), e1); w++; }
            if (k2) { write6(out, base + w, fs, (float)(b + 2), e2); w++; }
            if (k3) { write6(out, base + w, fs, (float)(b + 3), e3); }
            running += (int)__popcll(m0) + (int)__popcll(m1)
                     + (int)__popcll(m2) + (int)__popcll(m3);
        }
    }
}

// Fill padding region [min(total,MP), MP) and write npairs.
__global__ void k_pad(const int* __restrict__ total_p, float* __restrict__ out) {
    int k = blockIdx.x * blockDim.x + threadIdx.x;
    int total = *total_p;
    if (k == 0) out[6 * MP] = (float)total;
    int valid = total < MP ? total : MP;
    if (k >= valid && k < MP) {
        out[k]          = PADV;
        out[MP + k]     = PADV;
        out[2 * MP + k] = PADV;
        out[3 * MP + k] = PADV;
        out[4 * MP + k] = CUT2;
        out[5 * MP + k] = CUT2;
    }
}

extern "C" void kernel_launch(void* const* d_in, const int* in_sizes, int n_in,
                              void* d_out, int out_size, void* d_ws, size_t ws_size,
                              hipStream_t stream) {
    const float* coords = (const float*)d_in[0];
    float* out = (float*)d_out;

    // Workspace: counts [64000] | bsum [256] | total [+pad to 16] | SoA xyz
    // (each NPAD floats, 16B-aligned).
    int*   counts = (int*)d_ws;
    int*   bsum   = counts + NTOT;
    int*   total  = bsum + 256;
    float* xs     = (float*)(total + 16);
    float* ys     = xs + NPAD;
    float* zs     = ys + NPAD;

    k_transpose<<<(NPAD + 255) / 256, 256, 0, stream>>>(coords, xs, ys, zs);
    k_count<<<(NTOT * 64) / 256, 256, 0, stream>>>(xs, ys, zs, counts);
    k_scan_a<<<SCAN_BLOCKS, 256, 0, stream>>>(counts, bsum);
    k_scan_b<<<1, 256, 0, stream>>>(bsum, total);
    k_write<<<(NTOT * 64) / 256, 256, 0, stream>>>(xs, ys, zs, counts, bsum, out);
    k_pad<<<(MP + 255) / 256, 256, 0, stream>>>(total, out);
}

// Round 4
// 137.824 us; speedup vs baseline: 1.0860x; 1.0860x over previous
//
#include <hip/hip_runtime.h>

#define NSYS 64
#define NAT  1000
#define NTOT (NSYS * NAT)          // 64000
#define MP   2200000               // MAX_PAIRS
#define CUT2 25.0f                 // cutoff^2
#define PADV 64000.0f              // padding_value = n
#define SCAN_BLOCKS 250            // 250 * 256 == 64000 exactly
#define RPB  16                    // rows per block (1 wave per row, 1024 thr)
#define TILES ((NAT + RPB - 1) / RPB)   // 63 row-tiles per system

// Identical distance expression in count & write passes (must match bit-exactly
// so row offsets stay consistent). Inputs come from identical LDS contents.
__device__ __forceinline__ float dist2f(float xi, float yi, float zi,
                                        float xj, float yj, float zj) {
    float dx = xi - xj, dy = yi - yj, dz = zi - zj;
    return fmaf(dz, dz, fmaf(dy, dy, dx * dx));
}

// One block = (system, 16-row tile). Stage the system's AoS coords in LDS
// (stride-3 dword access: gcd(3,32)=1 -> at most 2-way bank alias = free).
// Wave w handles row r = tile*16+w; lane-strided j in (r, NAT).
__global__ __launch_bounds__(1024) void k_count(const float* __restrict__ coords,
                                                int* __restrict__ counts) {
    __shared__ float lc[NAT * 3];
    int s    = blockIdx.x / TILES;
    int tile = blockIdx.x % TILES;
    const float* cs = coords + s * (NAT * 3);
    for (int idx = threadIdx.x; idx < NAT * 3; idx += 1024) lc[idx] = cs[idx];
    __syncthreads();
    int w    = threadIdx.x >> 6;
    int lane = threadIdx.x & 63;
    int r    = tile * RPB + w;
    if (r >= NAT) return;                       // after the barrier
    float xi = lc[3 * r], yi = lc[3 * r + 1], zi = lc[3 * r + 2];
    int cnt = 0;
    for (int j = r + 1 + lane; j < NAT; j += 64) {
        float d2 = dist2f(xi, yi, zi, lc[3 * j], lc[3 * j + 1], lc[3 * j + 2]);
        cnt += (d2 < CUT2) ? 1 : 0;
    }
    for (int off = 32; off > 0; off >>= 1) cnt += __shfl_xor(cnt, off, 64);
    if (lane == 0) counts[s * NAT + r] = cnt;
}

// Level-1 scan: 250 blocks x 256 rows -> in-place block-exclusive + block sums.
__global__ void k_scan_a(int* __restrict__ counts, int* __restrict__ bsum) {
    __shared__ int tmp[256];
    int t = threadIdx.x;
    int g = blockIdx.x * 256 + t;
    int v = counts[g];
    tmp[t] = v;
    __syncthreads();
    for (int off = 1; off < 256; off <<= 1) {
        int u = (t >= off) ? tmp[t - off] : 0;
        __syncthreads();
        tmp[t] += u;
        __syncthreads();
    }
    counts[g] = tmp[t] - v;
    if (t == 255) bsum[blockIdx.x] = tmp[255];
}

// Level-2 scan: one block scans the 250 block sums, writes grand total.
__global__ void k_scan_b(int* __restrict__ bsum, int* __restrict__ total) {
    __shared__ int tmp[256];
    int t = threadIdx.x;
    int v = (t < SCAN_BLOCKS) ? bsum[t] : 0;
    tmp[t] = v;
    __syncthreads();
    for (int off = 1; off < 256; off <<= 1) {
        int u = (t >= off) ? tmp[t - off] : 0;
        __syncthreads();
        tmp[t] += u;
        __syncthreads();
    }
    if (t < SCAN_BLOCKS) bsum[t] = tmp[t] - v;
    if (t == 255) *total = tmp[255];
}

// Compact writer: same LDS eval as k_count; each kept pair writes ONLY
//   plane0[pos] = packed (grow<<10 | (j-r))   [as uint bits]
//   plane4[pos] = d2
// Both are those slots' final positions; k_expand fans out the rest.
__global__ __launch_bounds__(1024) void k_write(const float* __restrict__ coords,
                                                const int* __restrict__ counts,
                                                const int* __restrict__ bsum,
                                                float* __restrict__ out) {
    __shared__ float lc[NAT * 3];
    int s    = blockIdx.x / TILES;
    int tile = blockIdx.x % TILES;
    const float* cs = coords + s * (NAT * 3);
    for (int idx = threadIdx.x; idx < NAT * 3; idx += 1024) lc[idx] = cs[idx];
    __syncthreads();
    int w    = threadIdx.x >> 6;
    int lane = threadIdx.x & 63;
    int r    = tile * RPB + w;
    if (r >= NAT) return;
    float xi = lc[3 * r], yi = lc[3 * r + 1], zi = lc[3 * r + 2];
    int grow = s * NAT + r;
    int running = counts[grow] + bsum[grow >> 8];   // global exclusive prefix
    unsigned int* outU = (unsigned int*)out;
    unsigned long long lt = (1ull << lane) - 1ull;
    for (int j = r + 1 + lane; j < NAT; j += 64) {
        float d2 = dist2f(xi, yi, zi, lc[3 * j], lc[3 * j + 1], lc[3 * j + 2]);
        bool keep = d2 < CUT2;
        unsigned long long m = __ballot(keep);
        if (keep) {
            int pos = running + (int)__popcll(m & lt);
            if (pos < MP) {
                outU[pos]       = ((unsigned)grow << 10) | (unsigned)(j - r);
                out[4 * MP + pos] = d2;
            }
        }
        running += (int)__popcll(m);
    }
}

// Fan-out + padding, fully coalesced float4 stores. Thread k4 covers
// [k4, k4+4): reads ONLY its own plane0/plane4 slots (race-free), rewrites
// planes 0,1,2,3,5 everywhere, plane4 only where padding is needed.
// Out layout: [0)src [MP)dst [2MP)dst [3MP)src [4MP)d12 [5MP)d12 [6MP]npairs
__global__ void k_expand(const int* __restrict__ total_p, float* __restrict__ out) {
    int k4 = (blockIdx.x * 256 + threadIdx.x) * 4;
    if (k4 >= MP) return;
    int total = *total_p;
    if (k4 == 0) out[6 * MP] = (float)total;        // npairs (unclamped)
    int valid = total < MP ? total : MP;
    const unsigned* outU = (const unsigned*)out;
    uint4  p  = *(const uint4*)(outU + k4);
    float4 dv = *(const float4*)(out + 4 * MP + k4);
    float fs[4], fd[4], dd[4];
    unsigned pe[4] = {p.x, p.y, p.z, p.w};
    float    de[4] = {dv.x, dv.y, dv.z, dv.w};
#pragma unroll
    for (int e = 0; e < 4; e++) {
        int k = k4 + e;
        if (k < valid) {
            unsigned row = pe[e] >> 10;
            fs[e] = (float)row;
            fd[e] = (float)(row + (pe[e] & 1023u));
            dd[e] = de[e];
        } else {
            fs[e] = PADV; fd[e] = PADV; dd[e] = CUT2;
        }
    }
    float4 vs = {fs[0], fs[1], fs[2], fs[3]};
    float4 vd = {fd[0], fd[1], fd[2], fd[3]};
    float4 vv = {dd[0], dd[1], dd[2], dd[3]};
    *(float4*)(out + k4)          = vs;
    *(float4*)(out + MP + k4)     = vd;
    *(float4*)(out + 2 * MP + k4) = vd;
    *(float4*)(out + 3 * MP + k4) = vs;
    if (k4 + 4 > valid) *(float4*)(out + 4 * MP + k4) = vv;  // pad region only
    *(float4*)(out + 5 * MP + k4) = vv;
}

extern "C" void kernel_launch(void* const* d_in, const int* in_sizes, int n_in,
                              void* d_out, int out_size, void* d_ws, size_t ws_size,
                              hipStream_t stream) {
    const float* coords = (const float*)d_in[0];
    float* out = (float*)d_out;

    // Workspace: counts [64000 ints] | bsum [256] | total
    int* counts = (int*)d_ws;
    int* bsum   = counts + NTOT;
    int* total  = bsum + 256;

    int pair_blocks = NSYS * TILES;                 // 64 * 63 = 4032
    k_count<<<pair_blocks, 1024, 0, stream>>>(coords, counts);
    k_scan_a<<<SCAN_BLOCKS, 256, 0, stream>>>(counts, bsum);
    k_scan_b<<<1, 256, 0, stream>>>(bsum, total);
    k_write<<<pair_blocks, 1024, 0, stream>>>(coords, counts, bsum, out);
    k_expand<<<(MP / 4 + 255) / 256, 256, 0, stream>>>(total, out);
}

// Round 5
// 120.955 us; speedup vs baseline: 1.2374x; 1.1395x over previous
//
#include <hip/hip_runtime.h>

#define NSYS 64
#define NAT  1000
#define NTOT (NSYS * NAT)          // 64000
#define MP   2200000               // MAX_PAIRS
#define CUT2 25.0f                 // cutoff^2
#define PADV 64000.0f              // padding_value = n
#define SCAN_BLOCKS 250            // 250 * 256 == 64000 exactly
#define RPB  16                    // rows per block (1 wave per row, 1024 thr)
#define TILES ((NAT + RPB - 1) / RPB)   // 63 row-tiles per system
#define CAP  104                   // per-row record capacity (max ~57 expected)

__device__ __forceinline__ float dist2f(float xi, float yi, float zi,
                                        float xj, float yj, float zj) {
    float dx = xi - xj, dy = yi - yj, dz = zi - zj;
    return fmaf(dz, dz, fmaf(dy, dy, dx * dx));
}

// Single evaluation pass. One block = (system, 16-row tile); system coords
// staged in LDS (stride-3 dword = 2-way bank alias = free). Wave w handles
// row r; per kept pair, write (j-i, d2bits) at the row's record slot in
// (s,i,j) rank order (ballot/popcount), plus the row's true count.
__global__ __launch_bounds__(1024) void k_eval(const float* __restrict__ coords,
                                               int* __restrict__ counts,
                                               uint2* __restrict__ qbuf) {
    __shared__ float lc[NAT * 3];
    int s    = blockIdx.x / TILES;
    int tile = blockIdx.x % TILES;
    const float* cs = coords + s * (NAT * 3);
    for (int idx = threadIdx.x; idx < NAT * 3; idx += 1024) lc[idx] = cs[idx];
    __syncthreads();
    int w    = threadIdx.x >> 6;
    int lane = threadIdx.x & 63;
    int r    = tile * RPB + w;
    if (r >= NAT) return;                        // after the barrier
    float xi = lc[3 * r], yi = lc[3 * r + 1], zi = lc[3 * r + 2];
    int grow = s * NAT + r;
    uint2* q = qbuf + (size_t)grow * CAP;
    int running = 0;
    unsigned long long lt = (1ull << lane) - 1ull;
    for (int j = r + 1 + lane; j < NAT; j += 64) {
        float d2 = dist2f(xi, yi, zi, lc[3 * j], lc[3 * j + 1], lc[3 * j + 2]);
        bool keep = d2 < CUT2;
        unsigned long long m = __ballot(keep);
        if (keep) {
            int rank = running + (int)__popcll(m & lt);
            if (rank < CAP)
                q[rank] = make_uint2((unsigned)(j - r), __float_as_uint(d2));
        }
        running += (int)__popcll(m);
    }
    if (lane == 0) counts[grow] = running;
}

// Level-1 scan: block-exclusive prefix into offs[] (counts preserved) + sums.
__global__ void k_scan_a(const int* __restrict__ counts, int* __restrict__ offs,
                         int* __restrict__ bsum) {
    __shared__ int tmp[256];
    int t = threadIdx.x;
    int g = blockIdx.x * 256 + t;
    int v = counts[g];
    tmp[t] = v;
    __syncthreads();
    for (int off = 1; off < 256; off <<= 1) {
        int u = (t >= off) ? tmp[t - off] : 0;
        __syncthreads();
        tmp[t] += u;
        __syncthreads();
    }
    offs[g] = tmp[t] - v;
    if (t == 255) bsum[blockIdx.x] = tmp[255];
}

// Level-2 scan: one block scans the 250 block sums, writes grand total.
__global__ void k_scan_b(int* __restrict__ bsum, int* __restrict__ total) {
    __shared__ int tmp[256];
    int t = threadIdx.x;
    int v = (t < SCAN_BLOCKS) ? bsum[t] : 0;
    tmp[t] = v;
    __syncthreads();
    for (int off = 1; off < 256; off <<= 1) {
        int u = (t >= off) ? tmp[t - off] : 0;
        __syncthreads();
        tmp[t] += u;
        __syncthreads();
    }
    if (t < SCAN_BLOCKS) bsum[t] = tmp[t] - v;
    if (t == 255) *total = tmp[255];
}

// One wave per row: gather the row record, write all 6 planes at final
// positions (consecutive slots per row -> segment-coalesced stores).
// Out layout: [0)src [MP)dst [2MP)dst [3MP)src [4MP)d12 [5MP)d12 [6MP]npairs
__global__ void k_emit(const int* __restrict__ counts, const int* __restrict__ offs,
                       const int* __restrict__ bsum, const uint2* __restrict__ qbuf,
                       float* __restrict__ out) {
    int gt   = blockIdx.x * blockDim.x + threadIdx.x;
    int row  = gt >> 6;
    int lane = gt & 63;
    if (row >= NTOT) return;
    int off = offs[row] + bsum[row >> 8];        // global exclusive prefix
    int cnt = counts[row];
    if (cnt > CAP) cnt = CAP;
    const uint2* q = qbuf + (size_t)row * CAP;
    float fs = (float)row;
    for (int l = lane; l < cnt; l += 64) {
        uint2 e = q[l];
        int pos = off + l;
        if (pos < MP) {
            float fd = (float)(row + (int)e.x);
            float d2 = __uint_as_float(e.y);
            out[pos]          = fs;
            out[MP + pos]     = fd;
            out[2 * MP + pos] = fd;
            out[3 * MP + pos] = fs;
            out[4 * MP + pos] = d2;
            out[5 * MP + pos] = d2;
        }
    }
}

// Fill padding region [valid, MP) of all 6 planes + npairs. float4 fast path
// for fully-padded quads; element path for the straddling quad.
__global__ void k_pad(const int* __restrict__ total_p, float* __restrict__ out) {
    int k4 = (blockIdx.x * 256 + threadIdx.x) * 4;
    if (k4 >= MP) return;
    int total = *total_p;
    if (k4 == 0) out[6 * MP] = (float)total;     // npairs (unclamped)
    int valid = total < MP ? total : MP;
    if (k4 + 4 <= valid) return;                 // fully valid quad
    if (k4 >= valid) {
        float4 vp = {PADV, PADV, PADV, PADV};
        float4 vc = {CUT2, CUT2, CUT2, CUT2};
        *(float4*)(out + k4)          = vp;
        *(float4*)(out + MP + k4)     = vp;
        *(float4*)(out + 2 * MP + k4) = vp;
        *(float4*)(out + 3 * MP + k4) = vp;
        *(float4*)(out + 4 * MP + k4) = vc;
        *(float4*)(out + 5 * MP + k4) = vc;
    } else {                                     // straddling quad
#pragma unroll
        for (int e = 0; e < 4; e++) {
            int k = k4 + e;
            if (k >= valid && k < MP) {
                out[k]          = PADV;
                out[MP + k]     = PADV;
                out[2 * MP + k] = PADV;
                out[3 * MP + k] = PADV;
                out[4 * MP + k] = CUT2;
                out[5 * MP + k] = CUT2;
            }
        }
    }
}

extern "C" void kernel_launch(void* const* d_in, const int* in_sizes, int n_in,
                              void* d_out, int out_size, void* d_ws, size_t ws_size,
                              hipStream_t stream) {
    const float* coords = (const float*)d_in[0];
    float* out = (float*)d_out;

    // Workspace: counts[64000] | offs[64000] | bsum[256] | total[16 pad] |
    // qbuf uint2[64000*CAP] (8B-aligned: 128272 ints = 513088 B, /8 exact).
    int*   counts = (int*)d_ws;
    int*   offs   = counts + NTOT;
    int*   bsum   = offs + NTOT;
    int*   total  = bsum + 256;
    uint2* qbuf   = (uint2*)(total + 16);

    k_eval<<<NSYS * TILES, 1024, 0, stream>>>(coords, counts, qbuf);
    k_scan_a<<<SCAN_BLOCKS, 256, 0, stream>>>(counts, offs, bsum);
    k_scan_b<<<1, 256, 0, stream>>>(bsum, total);
    k_emit<<<(NTOT * 64) / 256, 256, 0, stream>>>(counts, offs, bsum, qbuf, out);
    k_pad<<<(MP / 4 + 255) / 256, 256, 0, stream>>>(total, out);
}

// Round 6
// 113.392 us; speedup vs baseline: 1.3200x; 1.0667x over previous
//
#include <hip/hip_runtime.h>

#define NSYS 64
#define NAT  1000
#define NTOT (NSYS * NAT)          // 64000
#define MP   2200000               // MAX_PAIRS
#define CUT2 25.0f                 // cutoff^2
#define PADV 64000.0f              // padding_value = n
#define SCAN_BLOCKS 250            // 250 * 256 == 64000 exactly
#define CAP  104                   // per-row record capacity (max ~57 expected)
#define EB   512                   // eval/emit blocks: 2 per CU, one round
#define LCN  1152                  // LDS atoms incl. overrun slack (j2 <= 1126)

__device__ __forceinline__ float dist2f(float xi, float yi, float zi,
                                        float xj, float yj, float zj) {
    float dx = xi - xj, dy = yi - yj, dz = zi - zj;
    return fmaf(dz, dz, fmaf(dy, dy, dx * dx));
}

// Persistent eval: block b = (system s = b>>3, stripe = b&7). Stage system
// coords once as float4 SoA in LDS; wave W = stripe*16+w handles rows
// r = W + 128t. Inner loop: 2 candidates per lane per iter (j, j+64), one
// ds_read_b128 each; exact (s,i,j) rank via 2 ballots. Emits per-row records
// (j-r, d2bits) into qbuf + true per-row counts.
__global__ __launch_bounds__(1024) void k_eval(const float* __restrict__ coords,
                                               int* __restrict__ counts,
                                               uint2* __restrict__ qbuf) {
    __shared__ float4 lc[LCN];
    int s      = blockIdx.x >> 3;
    int stripe = blockIdx.x & 7;
    const float* cs = coords + s * (NAT * 3);
    for (int a = threadIdx.x; a < NAT; a += 1024)
        lc[a] = make_float4(cs[3 * a], cs[3 * a + 1], cs[3 * a + 2], 0.0f);
    __syncthreads();
    int w    = threadIdx.x >> 6;
    int lane = threadIdx.x & 63;
    int W    = stripe * 16 + w;
    unsigned long long lt = (1ull << lane) - 1ull;
    for (int r = W; r < NAT; r += 128) {
        float4 ci = lc[r];
        int grow = s * NAT + r;
        uint2* q = qbuf + (size_t)grow * CAP;
        int running = 0;
        for (int jb = r + 1; jb < NAT; jb += 128) {   // wave-uniform bound
            int j  = jb + lane;                        // j  <= 1062 < LCN
            int j2 = j + 64;                           // j2 <= 1126 < LCN
            float4 c0 = lc[j];
            float4 c1 = lc[j2];
            float d0 = dist2f(ci.x, ci.y, ci.z, c0.x, c0.y, c0.z);
            float d1 = dist2f(ci.x, ci.y, ci.z, c1.x, c1.y, c1.z);
            bool k0 = (j  < NAT) && (d0 < CUT2);
            bool k1 = (j2 < NAT) && (d1 < CUT2);
            unsigned long long m0 = __ballot(k0);
            unsigned long long m1 = __ballot(k1);
            if (k0) {
                int rank = running + (int)__popcll(m0 & lt);
                if (rank < CAP)
                    q[rank] = make_uint2((unsigned)(j - r), __float_as_uint(d0));
            }
            int base1 = running + (int)__popcll(m0);
            if (k1) {
                int rank = base1 + (int)__popcll(m1 & lt);
                if (rank < CAP)
                    q[rank] = make_uint2((unsigned)(j2 - r), __float_as_uint(d1));
            }
            running = base1 + (int)__popcll(m1);
        }
        if (lane == 0) counts[grow] = running;
    }
}

// Level-1 scan: 250 blocks x 256 rows -> block-exclusive offs[] + block sums.
__global__ void k_scan_a(const int* __restrict__ counts, int* __restrict__ offs,
                         int* __restrict__ bsum) {
    __shared__ int tmp[256];
    int t = threadIdx.x;
    int g = blockIdx.x * 256 + t;
    int v = counts[g];
    tmp[t] = v;
    __syncthreads();
    for (int off = 1; off < 256; off <<= 1) {
        int u = (t >= off) ? tmp[t - off] : 0;
        __syncthreads();
        tmp[t] += u;
        __syncthreads();
    }
    offs[g] = tmp[t] - v;
    if (t == 255) bsum[blockIdx.x] = tmp[255];
}

// Fused level-2 scan + emit + pad. Each block re-scans the 250 block sums in
// LDS (cheap, replicated), emits rows GW + 8192t (GW = global wave id), then
// pads its strided slice of the tail quads. Block 0 writes npairs.
// Out layout: [0)src [MP)dst [2MP)dst [3MP)src [4MP)d12 [5MP)d12 [6MP]npairs
__global__ __launch_bounds__(1024) void k_emitpad(const int* __restrict__ counts,
                                                  const int* __restrict__ offs,
                                                  const int* __restrict__ bsum,
                                                  const uint2* __restrict__ qbuf,
                                                  float* __restrict__ out) {
    __shared__ int bpre[256];
    __shared__ int stot;
    int t = threadIdx.x;
    int v = 0;
    if (t < 256) {
        v = (t < SCAN_BLOCKS) ? bsum[t] : 0;
        bpre[t] = v;
    }
    __syncthreads();
    for (int off = 1; off < 256; off <<= 1) {       // all threads hit barriers
        int u = 0;
        if (t < 256 && t >= off) u = bpre[t - off];
        __syncthreads();
        if (t < 256) bpre[t] += u;
        __syncthreads();
    }
    int incl = (t < 256) ? bpre[t] : 0;
    __syncthreads();
    if (t < 256) bpre[t] = incl - v;                 // exclusive prefix
    if (t == 255) stot = incl;                       // grand total
    __syncthreads();

    // ---- emit ----
    int wv   = t >> 6;
    int lane = t & 63;
    int GW   = blockIdx.x * 16 + wv;                 // [0, 8192)
    for (int r = GW; r < NTOT; r += EB * 16) {
        int off = offs[r] + bpre[r >> 8];
        int cnt = counts[r];
        if (cnt > CAP) cnt = CAP;
        const uint2* q = qbuf + (size_t)r * CAP;
        float fs = (float)r;
        for (int l = lane; l < cnt; l += 64) {
            uint2 e = q[l];
            int pos = off + l;
            if (pos < MP) {
                float fd = (float)(r + (int)e.x);
                float d2 = __uint_as_float(e.y);
                out[pos]          = fs;
                out[MP + pos]     = fd;
                out[2 * MP + pos] = fd;
                out[3 * MP + pos] = fs;
                out[4 * MP + pos] = d2;
                out[5 * MP + pos] = d2;
            }
        }
    }

    // ---- pad tail [valid, MP) + npairs ----
    int total = stot;
    if (blockIdx.x == 0 && t == 0) out[6 * MP] = (float)total;
    int valid = total < MP ? total : MP;
    const int NQ = MP / 4;                           // 550000 quads
    for (int q4 = blockIdx.x * 1024 + t; q4 < NQ; q4 += EB * 1024) {
        int k4 = q4 * 4;
        if (k4 + 4 <= valid) continue;               // fully valid quad
        if (k4 >= valid) {
            float4 vp = {PADV, PADV, PADV, PADV};
            float4 vc = {CUT2, CUT2, CUT2, CUT2};
            *(float4*)(out + k4)          = vp;
            *(float4*)(out + MP + k4)     = vp;
            *(float4*)(out + 2 * MP + k4) = vp;
            *(float4*)(out + 3 * MP + k4) = vp;
            *(float4*)(out + 4 * MP + k4) = vc;
            *(float4*)(out + 5 * MP + k4) = vc;
        } else {                                     // straddling quad
#pragma unroll
            for (int e = 0; e < 4; e++) {
                int k = k4 + e;
                if (k >= valid && k < MP) {
                    out[k]          = PADV;
                    out[MP + k]     = PADV;
                    out[2 * MP + k] = PADV;
                    out[3 * MP + k] = PADV;
                    out[4 * MP + k] = CUT2;
                    out[5 * MP + k] = CUT2;
                }
            }
        }
    }
}

extern "C" void kernel_launch(void* const* d_in, const int* in_sizes, int n_in,
                              void* d_out, int out_size, void* d_ws, size_t ws_size,
                              hipStream_t stream) {
    const float* coords = (const float*)d_in[0];
    float* out = (float*)d_out;

    // Workspace: counts[64000] | offs[64000] | bsum[256] | pad to 8B | qbuf
    int*   counts = (int*)d_ws;
    int*   offs   = counts + NTOT;
    int*   bsum   = offs + NTOT;
    uint2* qbuf   = (uint2*)(bsum + 256);    // 128256 ints before = 8B-aligned

    k_eval<<<EB, 1024, 0, stream>>>(coords, counts, qbuf);
    k_scan_a<<<SCAN_BLOCKS, 256, 0, stream>>>(counts, offs, bsum);
    k_emitpad<<<EB, 1024, 0, stream>>>(counts, offs, bsum, qbuf, out);
}

// Round 7
// 113.092 us; speedup vs baseline: 1.3235x; 1.0026x over previous
//
#include <hip/hip_runtime.h>

#define NSYS 64
#define NAT  1000
#define NTOT (NSYS * NAT)          // 64000
#define MP   2200000               // MAX_PAIRS
#define CUT2 25.0f                 // cutoff^2
#define PADV 64000.0f              // padding_value = n
#define SCAN_BLOCKS 250            // 250 * 256 == 64000 exactly
#define CAP  104                   // per-row record capacity (max ~57 expected)
#define EB   512                   // eval blocks: 2 per CU, one round
#define LCN  1152                  // LDS atoms incl. overrun slack (j2 <= 1126)
#define NROWS 512                  // rows staged per emit block
#define POSB  4096                 // output positions per emit block

__device__ __forceinline__ float dist2f(float xi, float yi, float zi,
                                        float xj, float yj, float zj) {
    float dx = xi - xj, dy = yi - yj, dz = zi - zj;
    return fmaf(dz, dz, fmaf(dy, dy, dx * dx));
}

// popcount of mask over lanes strictly below me (2 VALU: v_mbcnt_lo/hi)
__device__ __forceinline__ int mbcnt(unsigned long long m) {
    unsigned lo = __builtin_amdgcn_mbcnt_lo((unsigned)m, 0u);
    return (int)__builtin_amdgcn_mbcnt_hi((unsigned)(m >> 32), lo);
}

// Persistent eval: block b = (system s = b>>3, stripe = b&7). Stage system
// coords once as float4 SoA in LDS; wave W = stripe*16+w handles rows
// r = (t odd ? 127-W : W) + 128t  (alternating stripe balances load).
// Inner loop: 2 candidates/lane/iter, bound checks peeled to a single tail
// iteration. Emits per-row records (j-r, d2bits) + true per-row counts.
__global__ __launch_bounds__(1024) void k_eval(const float* __restrict__ coords,
                                               int* __restrict__ counts,
                                               uint2* __restrict__ qbuf) {
    __shared__ float4 lc[LCN];
    int s      = blockIdx.x >> 3;
    int stripe = blockIdx.x & 7;
    const float* cs = coords + s * (NAT * 3);
    for (int a = threadIdx.x; a < LCN; a += 1024)
        lc[a] = (a < NAT)
              ? make_float4(cs[3 * a], cs[3 * a + 1], cs[3 * a + 2], 0.0f)
              : make_float4(1.0e30f, 1.0e30f, 1.0e30f, 0.0f);
    __syncthreads();
    int w    = threadIdx.x >> 6;
    int lane = threadIdx.x & 63;
    int W    = stripe * 16 + w;
    for (int t = 0;; t++) {
        int r = ((t & 1) ? (127 - W) : W) + (t << 7);
        if (r >= NAT) { if (((t & 1) ? W : (127 - W)) + (t << 7) >= NAT) break; else continue; }
        float4 ci = lc[r];
        int grow = s * NAT + r;
        uint2* q = qbuf + (size_t)grow * CAP;
        int running = 0;
        int jb = r + 1;
        // full iterations: j, j+64 both guaranteed < NAT
        for (; jb + 127 < NAT; jb += 128) {
            int j  = jb + lane;
            float4 c0 = lc[j];
            float4 c1 = lc[j + 64];
            float d0 = dist2f(ci.x, ci.y, ci.z, c0.x, c0.y, c0.z);
            float d1 = dist2f(ci.x, ci.y, ci.z, c1.x, c1.y, c1.z);
            bool k0 = d0 < CUT2;
            bool k1 = d1 < CUT2;
            unsigned long long m0 = __ballot(k0);
            unsigned long long m1 = __ballot(k1);
            if (k0) {
                int rank = running + mbcnt(m0);
                if (rank < CAP)
                    q[rank] = make_uint2((unsigned)(j - r), __float_as_uint(d0));
            }
            int base1 = running + (int)__popcll(m0);
            if (k1) {
                int rank = base1 + mbcnt(m1);
                if (rank < CAP)
                    q[rank] = make_uint2((unsigned)(j + 64 - r), __float_as_uint(d1));
            }
            running = base1 + (int)__popcll(m1);
        }
        if (jb < NAT) {                              // single checked tail iter
            int j  = jb + lane;
            int j2 = j + 64;
            float4 c0 = lc[j];
            float4 c1 = lc[j2];
            float d0 = dist2f(ci.x, ci.y, ci.z, c0.x, c0.y, c0.z);
            float d1 = dist2f(ci.x, ci.y, ci.z, c1.x, c1.y, c1.z);
            bool k0 = (j  < NAT) && (d0 < CUT2);
            bool k1 = (j2 < NAT) && (d1 < CUT2);
            unsigned long long m0 = __ballot(k0);
            unsigned long long m1 = __ballot(k1);
            if (k0) {
                int rank = running + mbcnt(m0);
                if (rank < CAP)
                    q[rank] = make_uint2((unsigned)(j - r), __float_as_uint(d0));
            }
            int base1 = running + (int)__popcll(m0);
            if (k1) {
                int rank = base1 + mbcnt(m1);
                if (rank < CAP)
                    q[rank] = make_uint2((unsigned)(j2 - r), __float_as_uint(d1));
            }
            running = base1 + (int)__popcll(m1);
        }
        if (lane == 0) counts[grow] = running;
    }
}

// Level-1 scan: 250 blocks x 256 rows -> block-exclusive offs[] + block sums.
__global__ void k_scan_a(const int* __restrict__ counts, int* __restrict__ offs,
                         int* __restrict__ bsum) {
    __shared__ int tmp[256];
    int t = threadIdx.x;
    int g = blockIdx.x * 256 + t;
    int v = counts[g];
    tmp[t] = v;
    __syncthreads();
    for (int off = 1; off < 256; off <<= 1) {
        int u = (t >= off) ? tmp[t - off] : 0;
        __syncthreads();
        tmp[t] += u;
        __syncthreads();
    }
    offs[g] = tmp[t] - v;
    if (t == 255) bsum[blockIdx.x] = tmp[255];
}

// Position-indexed emit + pad, fully coalesced. Block covers POSB=4096 output
// slots; thread covers 4 consecutive slots. Per block: scan bsum in LDS,
// binary-search start row (thread 0), stage 513 row offsets in LDS; per
// thread: LDS search + walk -> row, read record, assemble float4, store all
// 6 planes vectorized. Pad slots (p >= total) use constants in the same path.
// Out layout: [0)src [MP)dst [2MP)dst [3MP)src [4MP)d12 [5MP)d12 [6MP]npairs
__global__ __launch_bounds__(1024) void k_emit(const int* __restrict__ offs,
                                               const int* __restrict__ bsum,
                                               const uint2* __restrict__ qbuf,
                                               float* __restrict__ out) {
    __shared__ int bpre[256];
    __shared__ int lgoff[NROWS + 1];
    __shared__ int sh_r0, sh_tot;
    int t = threadIdx.x;
    int v = 0;
    if (t < 256) {
        v = (t < SCAN_BLOCKS) ? bsum[t] : 0;
        bpre[t] = v;
    }
    __syncthreads();
    for (int off = 1; off < 256; off <<= 1) {
        int u = 0;
        if (t < 256 && t >= off) u = bpre[t - off];
        __syncthreads();
        if (t < 256) bpre[t] += u;
        __syncthreads();
    }
    int incl = (t < 256) ? bpre[t] : 0;
    __syncthreads();
    if (t < 256) bpre[t] = incl - v;                 // exclusive prefix
    if (t == 255) sh_tot = incl;                     // grand total
    __syncthreads();
    int total = sh_tot;

    int p0 = blockIdx.x * POSB;
    if (t == 0) {
        // largest r in [0, NTOT] with goff(r) <= p0
        int lo = 0, hi = NTOT;
        while (lo < hi) {
            int mid = (lo + hi + 1) >> 1;
            int g = (mid < NTOT) ? offs[mid] + bpre[mid >> 8] : total;
            if (g <= p0) lo = mid; else hi = mid - 1;
        }
        sh_r0 = lo;
    }
    __syncthreads();
    int r0 = sh_r0;
    if (t <= NROWS) {
        int r = r0 + t;
        lgoff[t] = (r < NTOT) ? offs[r] + bpre[r >> 8] : total;
    }
    __syncthreads();

    if (blockIdx.x == 0 && t == 0) out[6 * MP] = (float)total;  // npairs
    int valid = total < MP ? total : MP;

    int p4 = p0 + t * 4;
    if (p4 >= MP) return;
    // search for p4's row in staged offsets, then walk for subsequent slots
    int k = 0;
    for (int step = 256; step; step >>= 1) {
        int nk = k + step;
        if (nk <= NROWS - 1 && lgoff[nk] <= p4) k = nk;
    }
    float fs[4], fd[4], dd[4];
#pragma unroll
    for (int e = 0; e < 4; e++) {
        int p = p4 + e;
        if (p < valid) {
            while (k < NROWS - 1 && lgoff[k + 1] <= p) k++;
            int row = r0 + k;
            int local = p - lgoff[k];
            if (local > CAP - 1) local = CAP - 1;    // count>CAP guard (P~0)
            uint2 rec = qbuf[(size_t)row * CAP + local];
            fs[e] = (float)row;
            fd[e] = (float)(row + (int)rec.x);
            dd[e] = __uint_as_float(rec.y);
        } else {
            fs[e] = PADV; fd[e] = PADV; dd[e] = CUT2;
        }
    }
    if (p4 + 4 <= MP) {
        float4 vs = {fs[0], fs[1], fs[2], fs[3]};
        float4 vd = {fd[0], fd[1], fd[2], fd[3]};
        float4 vv = {dd[0], dd[1], dd[2], dd[3]};
        *(float4*)(out + p4)          = vs;
        *(float4*)(out + MP + p4)     = vd;
        *(float4*)(out + 2 * MP + p4) = vd;
        *(float4*)(out + 3 * MP + p4) = vs;
        *(float4*)(out + 4 * MP + p4) = vv;
        *(float4*)(out + 5 * MP + p4) = vv;
    } else {
#pragma unroll
        for (int e = 0; e < 4; e++) {
            int p = p4 + e;
            if (p < MP) {
                out[p]          = fs[e];
                out[MP + p]     = fd[e];
                out[2 * MP + p] = fd[e];
                out[3 * MP + p] = fs[e];
                out[4 * MP + p] = dd[e];
                out[5 * MP + p] = dd[e];
            }
        }
    }
}

extern "C" void kernel_launch(void* const* d_in, const int* in_sizes, int n_in,
                              void* d_out, int out_size, void* d_ws, size_t ws_size,
                              hipStream_t stream) {
    const float* coords = (const float*)d_in[0];
    float* out = (float*)d_out;

    // Workspace: counts[64000] | offs[64000] | bsum[256] | qbuf (8B-aligned:
    // 128256 ints = 513024 B before it, divisible by 8)
    int*   counts = (int*)d_ws;
    int*   offs   = counts + NTOT;
    int*   bsum   = offs + NTOT;
    uint2* qbuf   = (uint2*)(bsum + 256);

    int emit_blocks = (MP + POSB - 1) / POSB;        // 538
    k_eval<<<EB, 1024, 0, stream>>>(coords, counts, qbuf);
    k_scan_a<<<SCAN_BLOCKS, 256, 0, stream>>>(counts, offs, bsum);
    k_emit<<<emit_blocks, 1024, 0, stream>>>(offs, bsum, qbuf, out);
}